// Round 15
// baseline (41.940 us; speedup 1.0000x reference)
//
#include <hip/hip_runtime.h>
#include <hip/hip_fp16.h>

#define NCELL 512
#define EPSF  1e-8f
#define FSCD  0.08838834764831845    // 128**-0.5 (exact double of python repr)

typedef float f32x2 __attribute__((ext_vector_type(2)));

// ---------------- lane-permute primitives (all within 16-lane DPP rows) -----
template<int CTRL>
__device__ __forceinline__ int idpp(int x){
  return __builtin_amdgcn_update_dpp(x, x, CTRL, 0xF, 0xF, false);
}
template<int CTRL>
__device__ __forceinline__ float fdpp(float x){
  return __int_as_float(idpp<CTRL>(__float_as_int(x)));
}
// f32 lane-xor within 16-lane rows
__device__ __forceinline__ float xorl1(float v){ return fdpp<0xB1>(v); }              // quad_perm [1,0,3,2]
__device__ __forceinline__ float xorl2(float v){ return fdpp<0x4E>(v); }              // quad_perm [2,3,0,1]
__device__ __forceinline__ float xorl4(float v){ return fdpp<0x1B>(fdpp<0x141>(v)); } // half_mirror(x^7) o quad[3,2,1,0](x^3)
__device__ __forceinline__ float xorl8(float v){ return fdpp<0x128>(v); }             // row_ror:8 == x^8 in 16
// packed variants: DPP each 32-bit half, keep pair adjacency for pk ops
template<int CTRL>
__device__ __forceinline__ f32x2 vdpp(f32x2 v){
  f32x2 r; r.x = fdpp<CTRL>(v.x); r.y = fdpp<CTRL>(v.y); return r;
}
__device__ __forceinline__ f32x2 vxor1(f32x2 v){ return vdpp<0xB1>(v); }
__device__ __forceinline__ f32x2 vxor2(f32x2 v){ return vdpp<0x4E>(v); }
__device__ __forceinline__ f32x2 vxor4(f32x2 v){ return vdpp<0x1B>(vdpp<0x141>(v)); }
__device__ __forceinline__ f32x2 vxor8(f32x2 v){ return vdpp<0x128>(v); }

// f32 butterfly reductions over a 16-lane row; bitwise lane-uniform.
__device__ __forceinline__ float redsum16f(float v){
  v += xorl1(v); v += xorl2(v); v += xorl4(v); v += xorl8(v); return v;
}
__device__ __forceinline__ float redmax16f(float v){
  v = fmaxf(v,xorl1(v)); v = fmaxf(v,xorl2(v));
  v = fmaxf(v,xorl4(v)); v = fmaxf(v,xorl8(v)); return v;
}

// ------- 128-pt FWHT, packed f32x2, 8 elems/lane (4 pairs), 16 lanes/row ----
__device__ __forceinline__ void fwht128v(f32x2 v[4], f32x2 sA, f32x2 sB,
                                         f32x2 sC, f32x2 sD){
  #pragma unroll
  for (int i = 0; i < 4; ++i) {
    float a = v[i].x, b = v[i].y;
    v[i].x = a + b; v[i].y = a - b;
  }
  { f32x2 t = v[0]; v[0] = t + v[1]; v[1] = t - v[1];
    t = v[2]; v[2] = t + v[3]; v[3] = t - v[3]; }
  { f32x2 t = v[0]; v[0] = t + v[2]; v[2] = t - v[2];
    t = v[1]; v[1] = t + v[3]; v[3] = t - v[3]; }
  #pragma unroll
  for (int i = 0; i < 4; ++i) { f32x2 o = vxor1(v[i]); v[i] = __builtin_elementwise_fma(sA, v[i], o); }
  #pragma unroll
  for (int i = 0; i < 4; ++i) { f32x2 o = vxor2(v[i]); v[i] = __builtin_elementwise_fma(sB, v[i], o); }
  #pragma unroll
  for (int i = 0; i < 4; ++i) { f32x2 o = vxor4(v[i]); v[i] = __builtin_elementwise_fma(sC, v[i], o); }
  #pragma unroll
  for (int i = 0; i < 4; ++i) { f32x2 o = vxor8(v[i]); v[i] = __builtin_elementwise_fma(sD, v[i], o); }
}

// -------- one-time LUT build kernel (writes uint2 LUT into workspace) -------
// Same reach construction as R8-R14, bit-identical f64 math.
__global__ __launch_bounds__(256) void lut_build(
    const float* __restrict__ bnd, const float* __restrict__ ctr,
    uint2* __restrict__ wlut)
{
  __shared__ double Bd[256];
  const int tid = threadIdx.x;
  if (tid < 255)  Bd[tid] = (double)bnd[tid];
  if (tid == 255) Bd[255] = __builtin_inf();
  __syncthreads();

  const double lo    = Bd[0] - 0.01;
  const double cw    = (Bd[254] + 0.01 - lo) * (1.0 / NCELL);
  const double scale = 1.0 / cw;
  const double epsg  = cw * 1e-3;

  const int c = blockIdx.x * 256 + tid;
  if (c >= NCELL) return;
  double wl = (c == 0)         ? -__builtin_inf() : fma((double)c,     cw, lo) - epsg;
  double wr = (c == NCELL - 1) ?  __builtin_inf() : fma((double)(c+1), cw, lo) + epsg;
  int n = 0;
  #pragma unroll
  for (int s = 128; s; s >>= 1) n += (Bd[n + s - 1] < wl) ? s : 0;  // n = #{B < wl}
  double b  = Bd[n];
  bool  has = (b < wr);
  float c_lo = ctr[n];
  float c_hi = ctr[has ? (n + 1) : n];
  uint2 e;
  e.x = __float_as_uint(has ? (float)b : __builtin_inff());
  e.y = ((unsigned)__half_as_ushort(__float2half_rn(c_hi)) << 16)
      |  (unsigned)__half_as_ushort(__float2half_rn(c_lo));
  wlut[c] = e;
}

__global__ __launch_bounds__(256) void tq_kernel(
    const float* __restrict__ x, const float* __restrict__ signs,
    const float* __restrict__ bnd, const float* __restrict__ ctr,
    const uint2* __restrict__ wlut, float* __restrict__ out, int nquads)
{
  // prologue: copy prebuilt LUT (4 KB) from workspace -> LDS. No f64, no
  // binary searches, one barrier.
  __shared__ uint2 lutE[NCELL];
  const int tid = threadIdx.x;
  lutE[tid]       = wlut[tid];
  lutE[tid + 256] = wlut[tid + 256];

  // addressing constants (recomputed identically to lut_build, f64 once)
  const double lo  = (double)bnd[0] - 0.01;
  const double cw  = ((double)bnd[254] + 0.01 - lo) * (1.0 / NCELL);
  const double scd = 1.0 / cw;
  const float scf  = (float)scd;
  const float nlsf = (float)(-lo * scd);
  __syncthreads();

  const int l   = tid & 63;
  const int li  = l & 15;         // lane within 16-lane row
  const int rw  = (l >> 4) & 3;   // row within wave (4 rows/wave)
  const int wid = tid >> 6;
  const float sAs = (l & 1) ? -1.f : 1.f;
  const float sBs = (l & 2) ? -1.f : 1.f;
  const float sCs = (l & 4) ? -1.f : 1.f;
  const float sDs = (l & 8) ? -1.f : 1.f;
  const f32x2 sAv = { sAs, sAs }, sBv = { sBs, sBs },
              sCv = { sCs, sCs }, sDv = { sDs, sDs };
  const float inv_maxcf = 1.0f / ctr[255];
  const float icmax = (float)(NCELL - 1);
  const float fscf  = (float)FSCD;

  const float4 sga = *reinterpret_cast<const float4*>(signs + 8 * li);
  const float4 sgb = *reinterpret_cast<const float4*>(signs + 8 * li + 4);
  const f32x2 sg[4] = { { sga.x, sga.y }, { sga.z, sga.w },
                        { sgb.x, sgb.y }, { sgb.z, sgb.w } };

  auto qcent = [&](float vf) -> float {
    float cf = fmaf(vf, scf, nlsf);
    cf = fminf(fmaxf(cf, 0.0f), icmax);
    int ic = (int)cf;
    uint2 e = lutE[ic];
    unsigned h = (__uint_as_float(e.x) < vf) ? (e.y >> 16) : (e.y & 0xFFFFu);
    return __half2float(__ushort_as_half((unsigned short)h));
  };

  const int stride = gridDim.x * 4;
  int t = blockIdx.x * 4 + wid;
  if (t >= nquads) return;

  const int base_off = rw * 128 + 8 * li;
  const float* xp = x + 4 * t * 128 + base_off;
  float4 xa = *reinterpret_cast<const float4*>(xp);
  float4 xb = *reinterpret_cast<const float4*>(xp + 4);

  while (true) {
    const int tn = t + stride;
    const bool more = (tn < nquads);
    const int tpf = more ? tn : t;
    const float* np_ = x + 4 * tpf * 128 + base_off;
    float4 na = *reinterpret_cast<const float4*>(np_);
    float4 nb = *reinterpret_cast<const float4*>(np_ + 4);

    f32x2 r[4];
    r[0] = f32x2{ xa.x, xa.y } * sg[0];
    r[1] = f32x2{ xa.z, xa.w } * sg[1];
    r[2] = f32x2{ xb.x, xb.y } * sg[2];
    r[3] = f32x2{ xb.z, xb.w } * sg[3];

    fwht128v(r, sAv, sBv, sCv, sDv);

    f32x2 ssv = r[0] * r[0];
    f32x2 abv = __builtin_elementwise_abs(r[0]);
    f32x2 mxv = abv, asv = abv;
    #pragma unroll
    for (int i = 1; i < 4; ++i) {
      ssv = __builtin_elementwise_fma(r[i], r[i], ssv);
      f32x2 a = __builtin_elementwise_abs(r[i]);
      mxv = __builtin_elementwise_max(mxv, a);
      asv = asv + a;
    }
    float ssf = ssv.x + ssv.y;
    float mxf = fmaxf(mxv.x, mxv.y);
    float asf = asv.x + asv.y;

    // norms via Parseval: ||x|| = sqrt(sum r^2)/sqrt(128)
    float nf = __builtin_amdgcn_sqrtf(redsum16f(ssf)) * fscf + EPSF;
    float kf = fscf * __builtin_amdgcn_rcpf(nf);

    float xmaxf  = redmax16f(mxf) * kf;
    float xmeanf = fmaf(redsum16f(asf) * 0.0078125f, kf, EPSF);
    bool  spiky  = xmaxf > 5.0f * xmeanf;
    float rmsf   = xmaxf * inv_maxcf;

    // pass 1
    float kd1f = kf * __builtin_amdgcn_rcpf(rmsf + EPSF);
    f32x2 c1[4];
    #pragma unroll
    for (int i = 0; i < 4; ++i) {
      c1[i].x = qcent(r[i].x * kd1f);
      c1[i].y = qcent(r[i].y * kd1f);
    }

    // gamma refine
    f32x2 nmv = r[0] * c1[0];
    f32x2 dnv = c1[0] * c1[0];
    #pragma unroll
    for (int i = 1; i < 4; ++i) {
      nmv = __builtin_elementwise_fma(r[i],  c1[i], nmv);
      dnv = __builtin_elementwise_fma(c1[i], c1[i], dnv);
    }
    float gamma1 = redsum16f(nmv.x + nmv.y) * kf *
                   __builtin_amdgcn_rcpf(redsum16f(dnv.x + dnv.y) + EPSF);

    // pass 2
    float kd2f = kf * __builtin_amdgcn_rcpf(gamma1 + EPSF);
    f32x2 c2[4];
    #pragma unroll
    for (int i = 0; i < 4; ++i) {
      c2[i].x = qcent(r[i].x * kd2f);
      c2[i].y = qcent(r[i].y * kd2f);
    }

    // reconstruct; fold gamma*FSC*norms into one pre-FWHT scalar (linearity)
    float g2s = (spiky ? rmsf : gamma1) * fscf * nf;
    const f32x2 g2v = { g2s, g2s };
    f32x2 y[4];
    #pragma unroll
    for (int i = 0; i < 4; ++i) y[i] = (spiky ? c1[i] : c2[i]) * g2v;
    fwht128v(y, sAv, sBv, sCv, sDv);

    #pragma unroll
    for (int i = 0; i < 4; ++i) y[i] = y[i] * sg[i];
    float4 oa, ob;
    oa.x = y[0].x; oa.y = y[0].y; oa.z = y[1].x; oa.w = y[1].y;
    ob.x = y[2].x; ob.y = y[2].y; ob.z = y[3].x; ob.w = y[3].y;
    float* op = out + 4 * t * 128 + base_off;
    *reinterpret_cast<float4*>(op)     = oa;
    *reinterpret_cast<float4*>(op + 4) = ob;

    if (!more) break;
    t = tn; xa = na; xb = nb;
  }
}

extern "C" void kernel_launch(void* const* d_in, const int* in_sizes, int n_in,
                              void* d_out, int out_size, void* d_ws, size_t ws_size,
                              hipStream_t stream) {
  const float* x     = (const float*)d_in[0];
  const float* signs = (const float*)d_in[1];
  // d_in[2] = wht (unused: Sylvester Hadamard applied as in-register FWHT)
  const float* bnd   = (const float*)d_in[3];
  const float* ctr   = (const float*)d_in[4];
  float* out = (float*)d_out;
  uint2* wlut = (uint2*)d_ws;                // 4 KB of workspace

  // 1) build LUT once (deterministic; rebuilt every call -> graph-safe)
  hipLaunchKernelGGL(lut_build, dim3((NCELL + 255) / 256), dim3(256), 0, stream,
                     bnd, ctr, wlut);

  // 2) main kernel
  int nrows  = out_size / 128;
  int nquads = nrows / 4;                    // 4 rows per wave
  int blocks = (nquads + 3) / 4;             // 4 waves per block
  if (blocks > 2048) blocks = 2048;
  hipLaunchKernelGGL(tq_kernel, dim3(blocks), dim3(256), 0, stream,
                     x, signs, bnd, ctr, wlut, out, nquads);
}

// Round 16
// 40.731 us; speedup vs baseline: 1.0297x; 1.0297x over previous
//
#include <hip/hip_runtime.h>
#include <hip/hip_fp16.h>

#define NCELL 512
#define EPSF  1e-8f
#define FSCD  0.08838834764831845    // 128**-0.5 (exact double of python repr)

typedef float f32x2 __attribute__((ext_vector_type(2)));

// ---------------- lane-permute primitives (all within 16-lane DPP rows) -----
template<int CTRL>
__device__ __forceinline__ int idpp(int x){
  return __builtin_amdgcn_update_dpp(x, x, CTRL, 0xF, 0xF, false);
}
template<int CTRL>
__device__ __forceinline__ float fdpp(float x){
  return __int_as_float(idpp<CTRL>(__float_as_int(x)));
}
// f32 lane-xor within 16-lane rows
__device__ __forceinline__ float xorl1(float v){ return fdpp<0xB1>(v); }              // quad_perm [1,0,3,2]
__device__ __forceinline__ float xorl2(float v){ return fdpp<0x4E>(v); }              // quad_perm [2,3,0,1]
__device__ __forceinline__ float xorl4(float v){ return fdpp<0x1B>(fdpp<0x141>(v)); } // half_mirror(x^7) o quad[3,2,1,0](x^3)
__device__ __forceinline__ float xorl8(float v){ return fdpp<0x128>(v); }             // row_ror:8 == x^8 in 16
// packed variants: DPP each 32-bit half, keep pair adjacency for pk ops
template<int CTRL>
__device__ __forceinline__ f32x2 vdpp(f32x2 v){
  f32x2 r; r.x = fdpp<CTRL>(v.x); r.y = fdpp<CTRL>(v.y); return r;
}
__device__ __forceinline__ f32x2 vxor1(f32x2 v){ return vdpp<0xB1>(v); }
__device__ __forceinline__ f32x2 vxor2(f32x2 v){ return vdpp<0x4E>(v); }
__device__ __forceinline__ f32x2 vxor4(f32x2 v){ return vdpp<0x1B>(vdpp<0x141>(v)); }
__device__ __forceinline__ f32x2 vxor8(f32x2 v){ return vdpp<0x128>(v); }

// f32 butterfly reductions over a 16-lane row; bitwise lane-uniform.
__device__ __forceinline__ float redsum16f(float v){
  v += xorl1(v); v += xorl2(v); v += xorl4(v); v += xorl8(v); return v;
}
__device__ __forceinline__ float redmax16f(float v){
  v = fmaxf(v,xorl1(v)); v = fmaxf(v,xorl2(v));
  v = fmaxf(v,xorl4(v)); v = fmaxf(v,xorl8(v)); return v;
}

// ------- 128-pt FWHT, packed f32x2, 8 elems/lane (4 pairs), 16 lanes/row ----
__device__ __forceinline__ void fwht128v(f32x2 v[4], f32x2 sA, f32x2 sB,
                                         f32x2 sC, f32x2 sD){
  #pragma unroll
  for (int i = 0; i < 4; ++i) {
    float a = v[i].x, b = v[i].y;
    v[i].x = a + b; v[i].y = a - b;
  }
  { f32x2 t = v[0]; v[0] = t + v[1]; v[1] = t - v[1];
    t = v[2]; v[2] = t + v[3]; v[3] = t - v[3]; }
  { f32x2 t = v[0]; v[0] = t + v[2]; v[2] = t - v[2];
    t = v[1]; v[1] = t + v[3]; v[3] = t - v[3]; }
  #pragma unroll
  for (int i = 0; i < 4; ++i) { f32x2 o = vxor1(v[i]); v[i] = __builtin_elementwise_fma(sA, v[i], o); }
  #pragma unroll
  for (int i = 0; i < 4; ++i) { f32x2 o = vxor2(v[i]); v[i] = __builtin_elementwise_fma(sB, v[i], o); }
  #pragma unroll
  for (int i = 0; i < 4; ++i) { f32x2 o = vxor4(v[i]); v[i] = __builtin_elementwise_fma(sC, v[i], o); }
  #pragma unroll
  for (int i = 0; i < 4; ++i) { f32x2 o = vxor8(v[i]); v[i] = __builtin_elementwise_fma(sD, v[i], o); }
}

__global__ __launch_bounds__(256) void tq_kernel(
    const float* __restrict__ x, const float* __restrict__ signs,
    const float* __restrict__ bnd, const float* __restrict__ ctr,
    float* __restrict__ out, int nquads)
{
  // One-gather searchsorted LUT, O(1)-DEPTH BUILD (no binary search):
  // thread i owns boundary index i; cells c whose reach-left wl(c) =
  // lo + c*cw - eps satisfies B[i-1] < wl <= B[i] belong to i (exact
  // inverse of n_lo = #{B < wl}). For those cells: b* = B[i],
  // has = B[i] < wr(c). Edge-rounding (~1e-13) self-corrects through the
  // stored-b* compare or costs <=1 bucket (<=3e-3 output) - negligible.
  __shared__ uint2 lutE[NCELL];   // 4 KB {f32 b*, f16 C_hi<<16 | f16 C_lo}
  const int tid = threadIdx.x;

  const double lo    = (double)bnd[0] - 0.01;
  const double cw    = ((double)bnd[254] + 0.01 - lo) * (1.0 / NCELL);
  const double scale = 1.0 / cw;
  const double epsg  = cw * 1e-3;

  {
    const int i = tid;
    double Bm1 = (i == 0)   ? -__builtin_inf() : (double)bnd[i - 1];
    double B0  = (i == 255) ?  __builtin_inf() : (double)bnd[i];
    float  ci  = ctr[i];
    float  cip = ctr[(i == 255) ? 255 : (i + 1)];
    int cs = (i == 0)   ? 0     : (int)floor((Bm1 - lo + epsg) * scale) + 1;
    int ce = (i == 255) ? NCELL : (int)floor((B0  - lo + epsg) * scale) + 1;
    cs = max(cs, 0); ce = min(ce, NCELL);
    for (int c = cs; c < ce; ++c) {
      double wr = (c == NCELL - 1) ? __builtin_inf()
                                   : fma((double)(c + 1), cw, lo) + epsg;
      bool has = (B0 < wr);
      uint2 e;
      e.x = __float_as_uint(has ? (float)B0 : __builtin_inff());
      e.y = ((unsigned)__half_as_ushort(__float2half_rn(has ? cip : ci)) << 16)
          |  (unsigned)__half_as_ushort(__float2half_rn(ci));
      lutE[c] = e;
    }
  }
  __syncthreads();

  const int l   = tid & 63;
  const int li  = l & 15;         // lane within 16-lane row
  const int rw  = (l >> 4) & 3;   // row within wave (4 rows/wave)
  const int wid = tid >> 6;
  const int t   = blockIdx.x * 4 + wid;   // ONE quad per wave, no loop
  if (t >= nquads) return;

  const float sAs = (l & 1) ? -1.f : 1.f;
  const float sBs = (l & 2) ? -1.f : 1.f;
  const float sCs = (l & 4) ? -1.f : 1.f;
  const float sDs = (l & 8) ? -1.f : 1.f;
  const f32x2 sAv = { sAs, sAs }, sBv = { sBs, sBs },
              sCv = { sCs, sCs }, sDv = { sDs, sDs };
  const float inv_maxcf = 1.0f / ctr[255];
  const float scf   = (float)scale;
  const float nlsf  = (float)(-lo * scale);
  const float icmax = (float)(NCELL - 1);
  const float fscf  = (float)FSCD;

  const float4 sga = *reinterpret_cast<const float4*>(signs + 8 * li);
  const float4 sgb = *reinterpret_cast<const float4*>(signs + 8 * li + 4);
  const f32x2 sg[4] = { { sga.x, sga.y }, { sga.z, sga.w },
                        { sgb.x, sgb.y }, { sgb.z, sgb.w } };

  auto qcent = [&](float vf) -> float {
    float cf = fmaf(vf, scf, nlsf);
    cf = fminf(fmaxf(cf, 0.0f), icmax);
    int ic = (int)cf;
    uint2 e = lutE[ic];
    unsigned h = (__uint_as_float(e.x) < vf) ? (e.y >> 16) : (e.y & 0xFFFFu);
    return __half2float(__ushort_as_half((unsigned short)h));
  };

  const int base_off = rw * 128 + 8 * li;
  const float* xp = x + 4 * t * 128 + base_off;
  float4 xa = *reinterpret_cast<const float4*>(xp);
  float4 xb = *reinterpret_cast<const float4*>(xp + 4);

  // sign fold (packed), then packed FWHT
  f32x2 r[4];
  r[0] = f32x2{ xa.x, xa.y } * sg[0];
  r[1] = f32x2{ xa.z, xa.w } * sg[1];
  r[2] = f32x2{ xb.x, xb.y } * sg[2];
  r[3] = f32x2{ xb.z, xb.w } * sg[3];

  fwht128v(r, sAv, sBv, sCv, sDv);

  // fused stats (packed accumulate, horizontal finish)
  f32x2 ssv = r[0] * r[0];
  f32x2 abv = __builtin_elementwise_abs(r[0]);
  f32x2 mxv = abv, asv = abv;
  #pragma unroll
  for (int i = 1; i < 4; ++i) {
    ssv = __builtin_elementwise_fma(r[i], r[i], ssv);
    f32x2 a = __builtin_elementwise_abs(r[i]);
    mxv = __builtin_elementwise_max(mxv, a);
    asv = asv + a;
  }
  float ssf = ssv.x + ssv.y;
  float mxf = fmaxf(mxv.x, mxv.y);
  float asf = asv.x + asv.y;

  // norms via Parseval: ||x|| = sqrt(sum r^2)/sqrt(128)
  float nf = __builtin_amdgcn_sqrtf(redsum16f(ssf)) * fscf + EPSF;
  float kf = fscf * __builtin_amdgcn_rcpf(nf);

  float xmaxf  = redmax16f(mxf) * kf;
  float xmeanf = fmaf(redsum16f(asf) * 0.0078125f, kf, EPSF);
  bool  spiky  = xmaxf > 5.0f * xmeanf;
  float rmsf   = xmaxf * inv_maxcf;

  // pass 1: v = r*(k/(rms+EPS))
  float kd1f = kf * __builtin_amdgcn_rcpf(rmsf + EPSF);
  f32x2 c1[4];
  #pragma unroll
  for (int i = 0; i < 4; ++i) {
    c1[i].x = qcent(r[i].x * kd1f);
    c1[i].y = qcent(r[i].y * kd1f);
  }

  // gamma refine (packed accumulate)
  f32x2 nmv = r[0] * c1[0];
  f32x2 dnv = c1[0] * c1[0];
  #pragma unroll
  for (int i = 1; i < 4; ++i) {
    nmv = __builtin_elementwise_fma(r[i],  c1[i], nmv);
    dnv = __builtin_elementwise_fma(c1[i], c1[i], dnv);
  }
  float gamma1 = redsum16f(nmv.x + nmv.y) * kf *
                 __builtin_amdgcn_rcpf(redsum16f(dnv.x + dnv.y) + EPSF);

  // pass 2
  float kd2f = kf * __builtin_amdgcn_rcpf(gamma1 + EPSF);
  f32x2 c2[4];
  #pragma unroll
  for (int i = 0; i < 4; ++i) {
    c2[i].x = qcent(r[i].x * kd2f);
    c2[i].y = qcent(r[i].y * kd2f);
  }

  // reconstruct; fold gamma*FSC*norms into one pre-FWHT scalar (linearity)
  float g2s = (spiky ? rmsf : gamma1) * fscf * nf;
  const f32x2 g2v = { g2s, g2s };
  f32x2 y[4];
  #pragma unroll
  for (int i = 0; i < 4; ++i) y[i] = (spiky ? c1[i] : c2[i]) * g2v;
  fwht128v(y, sAv, sBv, sCv, sDv);

  #pragma unroll
  for (int i = 0; i < 4; ++i) y[i] = y[i] * sg[i];
  float4 oa, ob;
  oa.x = y[0].x; oa.y = y[0].y; oa.z = y[1].x; oa.w = y[1].y;
  ob.x = y[2].x; ob.y = y[2].y; ob.z = y[3].x; ob.w = y[3].y;
  float* op = out + 4 * t * 128 + base_off;
  *reinterpret_cast<float4*>(op)     = oa;
  *reinterpret_cast<float4*>(op + 4) = ob;
}

extern "C" void kernel_launch(void* const* d_in, const int* in_sizes, int n_in,
                              void* d_out, int out_size, void* d_ws, size_t ws_size,
                              hipStream_t stream) {
  const float* x     = (const float*)d_in[0];
  const float* signs = (const float*)d_in[1];
  // d_in[2] = wht (unused: Sylvester Hadamard applied as in-register FWHT)
  const float* bnd   = (const float*)d_in[3];
  const float* ctr   = (const float*)d_in[4];
  float* out = (float*)d_out;

  int nrows  = out_size / 128;
  int nquads = nrows / 4;                    // 4 rows per wave
  int blocks = (nquads + 3) / 4;             // one quad per wave, one-shot blocks
  hipLaunchKernelGGL(tq_kernel, dim3(blocks), dim3(256), 0, stream,
                     x, signs, bnd, ctr, out, nquads);
}

// Round 17
// 39.245 us; speedup vs baseline: 1.0687x; 1.0379x over previous
//
#include <hip/hip_runtime.h>
#include <hip/hip_fp16.h>

#define NCELL 512
#define EPSF  1e-8f
#define FSCD  0.08838834764831845    // 128**-0.5 (exact double of python repr)

typedef float f32x2 __attribute__((ext_vector_type(2)));

// ---------------- lane-permute primitives (all within 16-lane DPP rows) -----
template<int CTRL>
__device__ __forceinline__ int idpp(int x){
  return __builtin_amdgcn_update_dpp(x, x, CTRL, 0xF, 0xF, false);
}
template<int CTRL>
__device__ __forceinline__ float fdpp(float x){
  return __int_as_float(idpp<CTRL>(__float_as_int(x)));
}
// f32 lane-xor within 16-lane rows
__device__ __forceinline__ float xorl1(float v){ return fdpp<0xB1>(v); }              // quad_perm [1,0,3,2]
__device__ __forceinline__ float xorl2(float v){ return fdpp<0x4E>(v); }              // quad_perm [2,3,0,1]
__device__ __forceinline__ float xorl4(float v){ return fdpp<0x1B>(fdpp<0x141>(v)); } // half_mirror(x^7) o quad[3,2,1,0](x^3)
__device__ __forceinline__ float xorl8(float v){ return fdpp<0x128>(v); }             // row_ror:8 == x^8 in 16
// packed variants: DPP each 32-bit half, keep pair adjacency for pk ops
template<int CTRL>
__device__ __forceinline__ f32x2 vdpp(f32x2 v){
  f32x2 r; r.x = fdpp<CTRL>(v.x); r.y = fdpp<CTRL>(v.y); return r;
}
__device__ __forceinline__ f32x2 vxor1(f32x2 v){ return vdpp<0xB1>(v); }
__device__ __forceinline__ f32x2 vxor2(f32x2 v){ return vdpp<0x4E>(v); }
__device__ __forceinline__ f32x2 vxor4(f32x2 v){ return vdpp<0x1B>(vdpp<0x141>(v)); }
__device__ __forceinline__ f32x2 vxor8(f32x2 v){ return vdpp<0x128>(v); }

// f32 butterfly reductions over a 16-lane row; bitwise lane-uniform.
__device__ __forceinline__ float redsum16f(float v){
  v += xorl1(v); v += xorl2(v); v += xorl4(v); v += xorl8(v); return v;
}
__device__ __forceinline__ float redmax16f(float v){
  v = fmaxf(v,xorl1(v)); v = fmaxf(v,xorl2(v));
  v = fmaxf(v,xorl4(v)); v = fmaxf(v,xorl8(v)); return v;
}

// ------- 128-pt FWHT, packed f32x2, 8 elems/lane (4 pairs), 16 lanes/row ----
__device__ __forceinline__ void fwht128v(f32x2 v[4], f32x2 sA, f32x2 sB,
                                         f32x2 sC, f32x2 sD){
  #pragma unroll
  for (int i = 0; i < 4; ++i) {
    float a = v[i].x, b = v[i].y;
    v[i].x = a + b; v[i].y = a - b;
  }
  { f32x2 t = v[0]; v[0] = t + v[1]; v[1] = t - v[1];
    t = v[2]; v[2] = t + v[3]; v[3] = t - v[3]; }
  { f32x2 t = v[0]; v[0] = t + v[2]; v[2] = t - v[2];
    t = v[1]; v[1] = t + v[3]; v[3] = t - v[3]; }
  #pragma unroll
  for (int i = 0; i < 4; ++i) { f32x2 o = vxor1(v[i]); v[i] = __builtin_elementwise_fma(sA, v[i], o); }
  #pragma unroll
  for (int i = 0; i < 4; ++i) { f32x2 o = vxor2(v[i]); v[i] = __builtin_elementwise_fma(sB, v[i], o); }
  #pragma unroll
  for (int i = 0; i < 4; ++i) { f32x2 o = vxor4(v[i]); v[i] = __builtin_elementwise_fma(sC, v[i], o); }
  #pragma unroll
  for (int i = 0; i < 4; ++i) { f32x2 o = vxor8(v[i]); v[i] = __builtin_elementwise_fma(sD, v[i], o); }
}

__global__ __launch_bounds__(256) void tq_kernel(
    const float* __restrict__ x, const float* __restrict__ signs,
    const float* __restrict__ bnd, const float* __restrict__ ctr,
    float* __restrict__ out, int nquads)
{
  // One-gather searchsorted LUT, O(1)-DEPTH BUILD (R16-validated):
  // thread i owns boundary index i; writes cells c with B[i-1] < wl(c) <= B[i]
  // (exact inverse of n_lo = #{B < wl}).  Entry {f32 b*, f16 C_hi | f16 C_lo}.
  __shared__ uint2 lutE[NCELL];   // 4 KB
  const int tid = threadIdx.x;

  const double lo    = (double)bnd[0] - 0.01;
  const double cw    = ((double)bnd[254] + 0.01 - lo) * (1.0 / NCELL);
  const double scale = 1.0 / cw;
  const double epsg  = cw * 1e-3;

  {
    const int i = tid;
    double Bm1 = (i == 0)   ? -__builtin_inf() : (double)bnd[i - 1];
    double B0  = (i == 255) ?  __builtin_inf() : (double)bnd[i];
    float  ci  = ctr[i];
    float  cip = ctr[(i == 255) ? 255 : (i + 1)];
    int cs = (i == 0)   ? 0     : (int)floor((Bm1 - lo + epsg) * scale) + 1;
    int ce = (i == 255) ? NCELL : (int)floor((B0  - lo + epsg) * scale) + 1;
    cs = max(cs, 0); ce = min(ce, NCELL);
    for (int c = cs; c < ce; ++c) {
      double wr = (c == NCELL - 1) ? __builtin_inf()
                                   : fma((double)(c + 1), cw, lo) + epsg;
      bool has = (B0 < wr);
      uint2 e;
      e.x = __float_as_uint(has ? (float)B0 : __builtin_inff());
      e.y = ((unsigned)__half_as_ushort(__float2half_rn(has ? cip : ci)) << 16)
          |  (unsigned)__half_as_ushort(__float2half_rn(ci));
      lutE[c] = e;
    }
  }
  __syncthreads();

  const int l   = tid & 63;
  const int li  = l & 15;         // lane within 16-lane row
  const int rw  = (l >> 4) & 3;   // row within wave (4 rows/wave)
  const int wid = tid >> 6;
  const float sAs = (l & 1) ? -1.f : 1.f;
  const float sBs = (l & 2) ? -1.f : 1.f;
  const float sCs = (l & 4) ? -1.f : 1.f;
  const float sDs = (l & 8) ? -1.f : 1.f;
  const f32x2 sAv = { sAs, sAs }, sBv = { sBs, sBs },
              sCv = { sCs, sCs }, sDv = { sDs, sDs };
  const float inv_maxcf = 1.0f / ctr[255];
  const float scf   = (float)scale;
  const float nlsf  = (float)(-lo * scale);
  const float icmax = (float)(NCELL - 1);
  const float fscf  = (float)FSCD;

  const float4 sga = *reinterpret_cast<const float4*>(signs + 8 * li);
  const float4 sgb = *reinterpret_cast<const float4*>(signs + 8 * li + 4);
  const f32x2 sg[4] = { { sga.x, sga.y }, { sga.z, sga.w },
                        { sgb.x, sgb.y }, { sgb.z, sgb.w } };

  auto qcent = [&](float vf) -> float {
    float cf = fmaf(vf, scf, nlsf);
    cf = fminf(fmaxf(cf, 0.0f), icmax);
    int ic = (int)cf;
    uint2 e = lutE[ic];
    unsigned h = (__uint_as_float(e.x) < vf) ? (e.y >> 16) : (e.y & 0xFFFFu);
    return __half2float(__ushort_as_half((unsigned short)h));
  };

  const int stride = gridDim.x * 4;
  int t = blockIdx.x * 4 + wid;
  if (t >= nquads) return;

  const int base_off = rw * 128 + 8 * li;
  const float* xp = x + 4 * t * 128 + base_off;
  float4 xa = *reinterpret_cast<const float4*>(xp);
  float4 xb = *reinterpret_cast<const float4*>(xp + 4);

  while (true) {
    const int tn = t + stride;
    const bool more = (tn < nquads);
    const int tpf = more ? tn : t;
    const float* np_ = x + 4 * tpf * 128 + base_off;
    float4 na = *reinterpret_cast<const float4*>(np_);
    float4 nb = *reinterpret_cast<const float4*>(np_ + 4);

    // sign fold (packed), then packed FWHT
    f32x2 r[4];
    r[0] = f32x2{ xa.x, xa.y } * sg[0];
    r[1] = f32x2{ xa.z, xa.w } * sg[1];
    r[2] = f32x2{ xb.x, xb.y } * sg[2];
    r[3] = f32x2{ xb.z, xb.w } * sg[3];

    fwht128v(r, sAv, sBv, sCv, sDv);

    // fused stats (packed accumulate, horizontal finish)
    f32x2 ssv = r[0] * r[0];
    f32x2 abv = __builtin_elementwise_abs(r[0]);
    f32x2 mxv = abv, asv = abv;
    #pragma unroll
    for (int i = 1; i < 4; ++i) {
      ssv = __builtin_elementwise_fma(r[i], r[i], ssv);
      f32x2 a = __builtin_elementwise_abs(r[i]);
      mxv = __builtin_elementwise_max(mxv, a);
      asv = asv + a;
    }
    float ssf = ssv.x + ssv.y;
    float mxf = fmaxf(mxv.x, mxv.y);
    float asf = asv.x + asv.y;

    // norms via Parseval: ||x|| = sqrt(sum r^2)/sqrt(128)
    float nf = __builtin_amdgcn_sqrtf(redsum16f(ssf)) * fscf + EPSF;
    float kf = fscf * __builtin_amdgcn_rcpf(nf);

    float xmaxf  = redmax16f(mxf) * kf;
    float xmeanf = fmaf(redsum16f(asf) * 0.0078125f, kf, EPSF);
    bool  spiky  = xmaxf > 5.0f * xmeanf;
    float rmsf   = xmaxf * inv_maxcf;

    // pass 1: v = r*(k/(rms+EPS))
    float kd1f = kf * __builtin_amdgcn_rcpf(rmsf + EPSF);
    f32x2 c1[4];
    #pragma unroll
    for (int i = 0; i < 4; ++i) {
      c1[i].x = qcent(r[i].x * kd1f);
      c1[i].y = qcent(r[i].y * kd1f);
    }

    // gamma refine (packed accumulate)
    f32x2 nmv = r[0] * c1[0];
    f32x2 dnv = c1[0] * c1[0];
    #pragma unroll
    for (int i = 1; i < 4; ++i) {
      nmv = __builtin_elementwise_fma(r[i],  c1[i], nmv);
      dnv = __builtin_elementwise_fma(c1[i], c1[i], dnv);
    }
    float gamma1 = redsum16f(nmv.x + nmv.y) * kf *
                   __builtin_amdgcn_rcpf(redsum16f(dnv.x + dnv.y) + EPSF);

    // pass 2
    float kd2f = kf * __builtin_amdgcn_rcpf(gamma1 + EPSF);
    f32x2 c2[4];
    #pragma unroll
    for (int i = 0; i < 4; ++i) {
      c2[i].x = qcent(r[i].x * kd2f);
      c2[i].y = qcent(r[i].y * kd2f);
    }

    // reconstruct; fold gamma*FSC*norms into one pre-FWHT scalar (linearity)
    float g2s = (spiky ? rmsf : gamma1) * fscf * nf;
    const f32x2 g2v = { g2s, g2s };
    f32x2 y[4];
    #pragma unroll
    for (int i = 0; i < 4; ++i) y[i] = (spiky ? c1[i] : c2[i]) * g2v;
    fwht128v(y, sAv, sBv, sCv, sDv);

    #pragma unroll
    for (int i = 0; i < 4; ++i) y[i] = y[i] * sg[i];
    float4 oa, ob;
    oa.x = y[0].x; oa.y = y[0].y; oa.z = y[1].x; oa.w = y[1].y;
    ob.x = y[2].x; ob.y = y[2].y; ob.z = y[3].x; ob.w = y[3].y;
    float* op = out + 4 * t * 128 + base_off;
    *reinterpret_cast<float4*>(op)     = oa;
    *reinterpret_cast<float4*>(op + 4) = ob;

    if (!more) break;
    t = tn; xa = na; xb = nb;
  }
}

extern "C" void kernel_launch(void* const* d_in, const int* in_sizes, int n_in,
                              void* d_out, int out_size, void* d_ws, size_t ws_size,
                              hipStream_t stream) {
  const float* x     = (const float*)d_in[0];
  const float* signs = (const float*)d_in[1];
  // d_in[2] = wht (unused: Sylvester Hadamard applied as in-register FWHT)
  const float* bnd   = (const float*)d_in[3];
  const float* ctr   = (const float*)d_in[4];
  float* out = (float*)d_out;

  int nrows  = out_size / 128;
  int nquads = nrows / 4;                    // 4 rows per wave
  int blocks = (nquads + 3) / 4;             // 4 waves per block, grid-stride x4
  if (blocks > 2048) blocks = 2048;
  hipLaunchKernelGGL(tq_kernel, dim3(blocks), dim3(256), 0, stream,
                     x, signs, bnd, ctr, out, nquads);
}